// Round 16
// baseline (451.360 us; speedup 1.0000x reference)
//
#include <hip/hip_runtime.h>

typedef unsigned short u16;
typedef __bf16 bf16x8 __attribute__((ext_vector_type(8)));
typedef float f32x4 __attribute__((ext_vector_type(4)));

// ---------- helpers ----------
__device__ __forceinline__ u16 f2bf(float f) {
  unsigned u = __builtin_bit_cast(unsigned, f);
  unsigned lsb = (u >> 16) & 1u;
  u += 0x7fffu + lsb;                 // round-to-nearest-even
  return (u16)(u >> 16);
}

// D.lo = bf16(lo), D.hi = bf16(hi) — single VALU op
__device__ __forceinline__ unsigned cvt_pk_bf16(float lo, float hi) {
  unsigned r;
  asm("v_cvt_pk_bf16_f32 %0, %1, %2" : "=v"(r) : "v"(lo), "v"(hi));
  return r;
}

__device__ __forceinline__ void gld_lds16(const u16* g, u16* l) {
  __builtin_amdgcn_global_load_lds(
      (__attribute__((address_space(1))) void*)g,
      (__attribute__((address_space(3))) void*)l, 16, 0, 0);
}

// ---------- LayerNorm ----------
__global__ __launch_bounds__(256) void ln_kernel(
    const float* __restrict__ x, u16* __restrict__ out,
    const float* __restrict__ alpha_p, const float* __restrict__ beta_p) {
  const int row = blockIdx.x;
  const int t = threadIdx.x;
  const float4 v = reinterpret_cast<const float4*>(x + (size_t)row * 1024)[t];
  float s = v.x + v.y + v.z + v.w;
  float sq = v.x * v.x + v.y * v.y + v.z * v.z + v.w * v.w;
#pragma unroll
  for (int off = 32; off > 0; off >>= 1) {
    s += __shfl_down(s, off);
    sq += __shfl_down(sq, off);
  }
  __shared__ float red[8];
  const int w = t >> 6;
  if ((t & 63) == 0) { red[w] = s; red[4 + w] = sq; }
  __syncthreads();
  const float ts = red[0] + red[1] + red[2] + red[3];
  const float tq = red[4] + red[5] + red[6] + red[7];
  const float mean = ts * (1.0f / 1024.0f);
  float var = (tq - ts * mean) * (1.0f / 1023.0f);
  var = fmaxf(var, 0.0f);
  const float rden = 1.0f / (sqrtf(var) + 1e-5f);
  const float a = alpha_p[0], bb = beta_p[0];
  uint2 ov;
  ov.x = cvt_pk_bf16(a * (v.x - mean) * rden + bb, a * (v.y - mean) * rden + bb);
  ov.y = cvt_pk_bf16(a * (v.z - mean) * rden + bb, a * (v.w - mean) * rden + bb);
  reinterpret_cast<uint2*>(out + (size_t)row * 1024)[t] = ov;
}

// ---------- weight convert fp32 [K][N] -> bf16 transposed [N][K], optional scale ----------
__global__ __launch_bounds__(256) void wcvt_t(
    const float* __restrict__ w, u16* __restrict__ wt, int K, int N, float scale) {
  __shared__ float tile[32][33];
  const int n0 = blockIdx.x * 32, k0 = blockIdx.y * 32;
  const int tx = threadIdx.x, ty = threadIdx.y;
#pragma unroll
  for (int i = 0; i < 4; ++i)
    tile[ty + i * 8][tx] = w[(size_t)(k0 + ty + i * 8) * N + n0 + tx];
  __syncthreads();
#pragma unroll
  for (int i = 0; i < 4; ++i)
    wt[(size_t)(n0 + ty + i * 8) * K + k0 + tx] = f2bf(tile[tx][ty + i * 8] * scale);
}

// ---------- bias concat (bq pre-scaled) ----------
__global__ __launch_bounds__(256) void pack_bias(
    const float* __restrict__ a, const float* __restrict__ b,
    const float* __restrict__ c, float* __restrict__ o, float qscale) {
  const int i = blockIdx.x * 256 + threadIdx.x;
  o[i] = (i < 1024) ? a[i] * qscale : ((i < 2048) ? b[i - 1024] : c[i - 2048]);
}

// ---------- mask bias (log2 domain) + per-batch all-live flag ----------
__global__ __launch_bounds__(256) void mk_mbias(
    const int* __restrict__ mask, float* __restrict__ mb, int* __restrict__ flags) {
  const int b = blockIdx.x, t = threadIdx.x;
  __shared__ int bad;
  if (t == 0) bad = 0;
  __syncthreads();
  int loc = 0;
#pragma unroll
  for (int i = 0; i < 8; ++i) {
    const int idx = b * 2048 + t * 8 + i;
    const int mv = mask[idx];
    mb[idx] = mv ? 0.f : -1.4427e9f;
    loc |= (mv == 0);
  }
  if (loc) atomicOr(&bad, 1);
  __syncthreads();
  if (t == 0) flags[b] = !bad;
}

// ---------- GEMM ring-3 (proven): counted vmcnt, 512 threads, BM=128/BN=256 ----------
// EPI 2: bf16 relu out.  EPI 3: QKV split + V-transpose.
template <int EPI>
__global__ __launch_bounds__(512, 4) void gemm8(
    const u16* __restrict__ A, const u16* __restrict__ Bt,
    const float* __restrict__ bias, const float* __restrict__ res,
    void* __restrict__ Cout, u16* __restrict__ vt, int M, int N, int K) {
  constexpr int BM = 128, BN = 256;
  constexpr int MF = 4;
  extern __shared__ u16 smem[];             // [3][BM*32] A + [3][BN*32] B
  u16* Asb = smem;
  u16* Bsb = smem + 3 * BM * 32;

  const int tid = threadIdx.x;
  const int l = tid & 63;
  const int w = tid >> 6;
  const int wr = w >> 2, wc = w & 3;
  const int gx = gridDim.x;
  int id = blockIdx.y * gx + blockIdx.x;
  const int nwg = gx * gridDim.y;
  id = (id & 7) * (nwg >> 3) + (id >> 3);
  const int n0 = (id % gx) * BN;
  const int m0 = (id / gx) * BM;
  const int lr = l & 15, lg = l >> 4;
  const int koff = (lg ^ ((lr >> 1) & 3)) * 8;

  f32x4 acc[MF][4];
#pragma unroll
  for (int i = 0; i < MF; ++i)
#pragma unroll
    for (int j = 0; j < 4; ++j) acc[i][j] = f32x4{0.f, 0.f, 0.f, 0.f};

  const u16* aSrc;
  int aOff;
  {
    const int ci = tid;
    const int row = ci >> 2, c = ci & 3;
    const int sc = c ^ ((row >> 1) & 3);
    aSrc = A + (size_t)(m0 + row) * K + sc * 8;
    aOff = ci * 8;
  }
  const u16* bSrc[2];
  int bOff[2];
#pragma unroll
  for (int i = 0; i < 2; ++i) {
    const int ci = tid + i * 512;
    const int row = ci >> 2, c = ci & 3;
    const int sc = c ^ ((row >> 1) & 3);
    bSrc[i] = Bt + (size_t)(n0 + row) * K + sc * 8;
    bOff[i] = ci * 8;
  }

  const int NT = K >> 5;
  gld_lds16(aSrc, Asb + aOff);
#pragma unroll
  for (int i = 0; i < 2; ++i) gld_lds16(bSrc[i], Bsb + bOff[i]);
  gld_lds16(aSrc + 32, Asb + BM * 32 + aOff);
#pragma unroll
  for (int i = 0; i < 2; ++i) gld_lds16(bSrc[i] + 32, Bsb + BN * 32 + bOff[i]);
  asm volatile("s_waitcnt vmcnt(3)" ::: "memory");
  __builtin_amdgcn_s_barrier();

  int cur = 0;
  for (int t = 0; t < NT; ++t) {
    const int nx2 = (cur + 2 >= 3) ? cur - 1 : cur + 2;
    if (t + 2 < NT) {
      const int ko = (t + 2) * 32;
      gld_lds16(aSrc + ko, Asb + nx2 * BM * 32 + aOff);
#pragma unroll
      for (int i = 0; i < 2; ++i) gld_lds16(bSrc[i] + ko, Bsb + nx2 * BN * 32 + bOff[i]);
    }
    const u16* Ab = Asb + cur * BM * 32;
    const u16* Bb = Bsb + cur * BN * 32;
    bf16x8 a[MF], b[4];
#pragma unroll
    for (int mf = 0; mf < MF; ++mf)
      a[mf] = *reinterpret_cast<const bf16x8*>(&Ab[(wr * (BM / 2) + mf * 16 + lr) * 32 + koff]);
#pragma unroll
    for (int nf = 0; nf < 4; ++nf)
      b[nf] = *reinterpret_cast<const bf16x8*>(&Bb[(wc * 64 + nf * 16 + lr) * 32 + koff]);
    __builtin_amdgcn_s_setprio(1);
#pragma unroll
    for (int mf = 0; mf < MF; ++mf)
#pragma unroll
      for (int nf = 0; nf < 4; ++nf)
        acc[mf][nf] = __builtin_amdgcn_mfma_f32_16x16x32_bf16(a[mf], b[nf], acc[mf][nf], 0, 0, 0);
    __builtin_amdgcn_s_setprio(0);
    if (t + 2 < NT) asm volatile("s_waitcnt vmcnt(3)" ::: "memory");
    else asm volatile("s_waitcnt vmcnt(0)" ::: "memory");
    __builtin_amdgcn_s_barrier();
    cur = (cur + 1 >= 3) ? 0 : cur + 1;
  }

  if (EPI == 3 && n0 >= 2048) {
#pragma unroll
    for (int mf = 0; mf < MF; ++mf) {
#pragma unroll
      for (int nf = 0; nf < 4; ++nf) {
        const int col = n0 + wc * 64 + nf * 16 + lr;
        const float bv = bias[col];
        const int row0 = m0 + wr * (BM / 2) + mf * 16 + lg * 4;
        const int bb = row0 >> 11, s0 = row0 & 2047;
        const int d = col - 2048;
        uint2 pv;
        pv.x = cvt_pk_bf16(acc[mf][nf][0] + bv, acc[mf][nf][1] + bv);
        pv.y = cvt_pk_bf16(acc[mf][nf][2] + bv, acc[mf][nf][3] + bv);
        *reinterpret_cast<uint2*>(vt + ((size_t)bb * 1024 + d) * 2048 + s0) = pv;
      }
    }
    return;
  }

#pragma unroll
  for (int mf = 0; mf < MF; ++mf) {
#pragma unroll
    for (int nf = 0; nf < 4; ++nf) {
      const int col = n0 + wc * 64 + nf * 16 + lr;
      const float bv = bias[col];
#pragma unroll
      for (int j = 0; j < 4; ++j) {
        const int row = m0 + wr * (BM / 2) + mf * 16 + lg * 4 + j;
        const size_t idx = (size_t)row * N + col;
        const float vv = acc[mf][nf][j] + bv;
        if (EPI == 2)
          ((u16*)Cout)[idx] = f2bf(fmaxf(vv, 0.f));
        else
          ((u16*)Cout)[idx] = f2bf(vv);
      }
    }
  }
}

// ---------- GEMM ring-4, 2 tiles per barrier (for 1-block/CU dispatches) ----------
// EPI 1: f32 out = acc+bias+res.  BM=128/BN=256, 512 threads, VMC=3 loads/tile.
__global__ __launch_bounds__(512, 4) void gemm9(
    const u16* __restrict__ A, const u16* __restrict__ Bt,
    const float* __restrict__ bias, const float* __restrict__ res,
    float* __restrict__ Cout, int M, int N, int K) {
  constexpr int BM = 128, BN = 256;
  constexpr int MF = 4;
  extern __shared__ u16 smem[];             // [4][BM*32] A + [4][BN*32] B
  u16* Asb = smem;
  u16* Bsb = smem + 4 * BM * 32;

  const int tid = threadIdx.x;
  const int l = tid & 63;
  const int w = tid >> 6;
  const int wr = w >> 2, wc = w & 3;
  const int gx = gridDim.x;
  int id = blockIdx.y * gx + blockIdx.x;
  const int nwg = gx * gridDim.y;
  id = (id & 7) * (nwg >> 3) + (id >> 3);
  const int n0 = (id % gx) * BN;
  const int m0 = (id / gx) * BM;
  const int lr = l & 15, lg = l >> 4;
  const int koff = (lg ^ ((lr >> 1) & 3)) * 8;

  f32x4 acc[MF][4];
#pragma unroll
  for (int i = 0; i < MF; ++i)
#pragma unroll
    for (int j = 0; j < 4; ++j) acc[i][j] = f32x4{0.f, 0.f, 0.f, 0.f};

  const u16* aSrc;
  int aOff;
  {
    const int ci = tid;
    const int row = ci >> 2, c = ci & 3;
    const int sc = c ^ ((row >> 1) & 3);
    aSrc = A + (size_t)(m0 + row) * K + sc * 8;
    aOff = ci * 8;
  }
  const u16* bSrc[2];
  int bOff[2];
#pragma unroll
  for (int i = 0; i < 2; ++i) {
    const int ci = tid + i * 512;
    const int row = ci >> 2, c = ci & 3;
    const int sc = c ^ ((row >> 1) & 3);
    bSrc[i] = Bt + (size_t)(n0 + row) * K + sc * 8;
    bOff[i] = ci * 8;
  }

  const int NT = K >> 5;                    // even for K in {1024, 4096}
  // prologue: stage tiles 0 and 1
  gld_lds16(aSrc, Asb + aOff);
#pragma unroll
  for (int i = 0; i < 2; ++i) gld_lds16(bSrc[i], Bsb + bOff[i]);
  gld_lds16(aSrc + 32, Asb + BM * 32 + aOff);
#pragma unroll
  for (int i = 0; i < 2; ++i) gld_lds16(bSrc[i] + 32, Bsb + BN * 32 + bOff[i]);

  for (int t = 0; t < NT; t += 2) {
    const int b0 = t & 3, b1 = (t + 1) & 3, b2 = (t + 2) & 3, b3 = (t + 3) & 3;
    // wait: stage(t) landed (stage(t+1)'s 3 loads may remain outstanding)
    if (t + 2 < NT) asm volatile("s_waitcnt vmcnt(3)" ::: "memory");
    else asm volatile("s_waitcnt vmcnt(3)" ::: "memory");
    // one barrier per 2 tiles: bufs b2,b3 (written below) were last read 2 iters ago
    __builtin_amdgcn_s_barrier();
    if (t + 2 < NT) {
      const int ko2 = (t + 2) * 32;
      gld_lds16(aSrc + ko2, Asb + b2 * BM * 32 + aOff);
#pragma unroll
      for (int i = 0; i < 2; ++i) gld_lds16(bSrc[i] + ko2, Bsb + b2 * BN * 32 + bOff[i]);
      if (t + 3 < NT) {
        const int ko3 = (t + 3) * 32;
        gld_lds16(aSrc + ko3, Asb + b3 * BM * 32 + aOff);
#pragma unroll
        for (int i = 0; i < 2; ++i) gld_lds16(bSrc[i] + ko3, Bsb + b3 * BN * 32 + bOff[i]);
      }
    }
    // compute tile t
    {
      const u16* Ab = Asb + b0 * BM * 32;
      const u16* Bb = Bsb + b0 * BN * 32;
      bf16x8 a[MF], b[4];
#pragma unroll
      for (int mf = 0; mf < MF; ++mf)
        a[mf] = *reinterpret_cast<const bf16x8*>(&Ab[(wr * (BM / 2) + mf * 16 + lr) * 32 + koff]);
#pragma unroll
      for (int nf = 0; nf < 4; ++nf)
        b[nf] = *reinterpret_cast<const bf16x8*>(&Bb[(wc * 64 + nf * 16 + lr) * 32 + koff]);
      __builtin_amdgcn_s_setprio(1);
#pragma unroll
      for (int mf = 0; mf < MF; ++mf)
#pragma unroll
        for (int nf = 0; nf < 4; ++nf)
          acc[mf][nf] = __builtin_amdgcn_mfma_f32_16x16x32_bf16(a[mf], b[nf], acc[mf][nf], 0, 0, 0);
      __builtin_amdgcn_s_setprio(0);
    }
    // wait: stage(t+1) landed (stage(t+2),(t+3) = 6 loads may remain outstanding)
    if (t + 2 < NT) asm volatile("s_waitcnt vmcnt(6)" ::: "memory");
    else asm volatile("s_waitcnt vmcnt(0)" ::: "memory");
    // compute tile t+1
    {
      const u16* Ab = Asb + b1 * BM * 32;
      const u16* Bb = Bsb + b1 * BN * 32;
      bf16x8 a[MF], b[4];
#pragma unroll
      for (int mf = 0; mf < MF; ++mf)
        a[mf] = *reinterpret_cast<const bf16x8*>(&Ab[(wr * (BM / 2) + mf * 16 + lr) * 32 + koff]);
#pragma unroll
      for (int nf = 0; nf < 4; ++nf)
        b[nf] = *reinterpret_cast<const bf16x8*>(&Bb[(wc * 64 + nf * 16 + lr) * 32 + koff]);
      __builtin_amdgcn_s_setprio(1);
#pragma unroll
      for (int mf = 0; mf < MF; ++mf)
#pragma unroll
        for (int nf = 0; nf < 4; ++nf)
          acc[mf][nf] = __builtin_amdgcn_mfma_f32_16x16x32_bf16(a[mf], b[nf], acc[mf][nf], 0, 0, 0);
      __builtin_amdgcn_s_setprio(0);
    }
  }

#pragma unroll
  for (int mf = 0; mf < MF; ++mf) {
#pragma unroll
    for (int nf = 0; nf < 4; ++nf) {
      const int col = n0 + wc * 64 + nf * 16 + lr;
      const float bv = bias[col];
#pragma unroll
      for (int j = 0; j < 4; ++j) {
        const int row = m0 + wr * (BM / 2) + mf * 16 + lg * 4 + j;
        const size_t idx = (size_t)row * N + col;
        Cout[idx] = acc[mf][nf][j] + bv + res[idx];
      }
    }
  }
}

// ---------- flash attention: 8 waves, 256 q-rows/block, dbuf K/V, 32KB LDS ----------
__global__ __launch_bounds__(512, 4) void attn_fwd9(
    const u16* __restrict__ qkv, const u16* __restrict__ vt,
    const float* __restrict__ mbias, const int* __restrict__ flags,
    u16* __restrict__ ctx) {
  __shared__ u16 Ks[2][64 * 64];
  __shared__ u16 Vs[2][64 * 64];
  const int tid = threadIdx.x;
  const int l = tid & 63;
  const int w = tid >> 6;                   // 0..7
  const int p = blockIdx.y * 8 + blockIdx.x;
  const int idx = p >> 3;                   // 0..63
  const int bh = (p & 7) * 8 + (idx >> 3);  // 0..63
  const int qx = idx & 7;                   // 0..7
  const int b = bh >> 4, h = bh & 15;
  const int r0 = qx * 256 + w * 32;
  const int lr = l & 15, lg = l >> 4;

  const u16* qb = qkv + (size_t)b * 2048 * 3072 + h * 64;
  const u16* kp = qb + 1024;
  const u16* vb = vt + ((size_t)b * 1024 + h * 64) * 2048;
  const float* mb = mbias + (size_t)b * 2048;
  const int allLive = flags[b];

  bf16x8 qf[2][2];
#pragma unroll
  for (int m = 0; m < 2; ++m)
#pragma unroll
    for (int ks = 0; ks < 2; ++ks)
      qf[m][ks] = *reinterpret_cast<const bf16x8*>(
          qb + (size_t)(r0 + m * 16 + lr) * 3072 + ks * 32 + lg * 8);

  bf16x8 ones;
#pragma unroll
  for (int e = 0; e < 8; ++e) ones[e] = (__bf16)1.0f;

  float mrun[2] = {-1e30f, -1e30f};
  f32x4 osum[2];
  f32x4 o[2][4];
#pragma unroll
  for (int m = 0; m < 2; ++m) {
    osum[m] = f32x4{0.f, 0.f, 0.f, 0.f};
#pragma unroll
    for (int d = 0; d < 4; ++d) o[m][d] = f32x4{0.f, 0.f, 0.f, 0.f};
  }

  const int srow = tid >> 3, scc = tid & 7;
  const int ssc = scc ^ (srow & 7);
  const u16* kS = kp + (size_t)srow * 3072 + ssc * 8;
  const u16* vS = vb + (size_t)srow * 2048 + ssc * 8;
  gld_lds16(kS, &Ks[0][tid * 8]);
  gld_lds16(vS, &Vs[0][tid * 8]);
  asm volatile("s_waitcnt vmcnt(0)" ::: "memory");
  __syncthreads();

  union U8 { unsigned u[4]; bf16x8 v; };

  int cur = 0;
  for (int t = 0; t < 32; ++t) {
    const int kb0 = t * 64;
    if (t + 1 < 32) {
      const int nb = kb0 + 64;
      gld_lds16(kS + (size_t)nb * 3072, &Ks[cur ^ 1][tid * 8]);
      gld_lds16(vS + nb, &Vs[cur ^ 1][tid * 8]);
    }

    f32x4 st[2][4];
    __builtin_amdgcn_s_setprio(1);
#pragma unroll
    for (int cf = 0; cf < 4; ++cf) {
      const int krow = cf * 16 + lr;
      const int ch0 = lg ^ (krow & 7);
      const int ch1 = (4 + lg) ^ (krow & 7);
      const bf16x8 kf0 = *reinterpret_cast<const bf16x8*>(&Ks[cur][krow * 64 + ch0 * 8]);
      const bf16x8 kf1 = *reinterpret_cast<const bf16x8*>(&Ks[cur][krow * 64 + ch1 * 8]);
#pragma unroll
      for (int m = 0; m < 2; ++m) {
        f32x4 acc = __builtin_amdgcn_mfma_f32_16x16x32_bf16(kf0, qf[m][0],
                                                            f32x4{0.f, 0.f, 0.f, 0.f}, 0, 0, 0);
        st[m][cf] = __builtin_amdgcn_mfma_f32_16x16x32_bf16(kf1, qf[m][1], acc, 0, 0, 0);
      }
    }
    __builtin_amdgcn_s_setprio(0);

    if (!allLive) {
#pragma unroll
      for (int cf = 0; cf < 4; ++cf) {
        const float4 m4 = *reinterpret_cast<const float4*>(mb + kb0 + cf * 16 + lg * 4);
#pragma unroll
        for (int m = 0; m < 2; ++m) {
          st[m][cf][0] += m4.x;
          st[m][cf][1] += m4.y;
          st[m][cf][2] += m4.z;
          st[m][cf][3] += m4.w;
        }
      }
    }

    bf16x8 paA[2], paB[2];
#pragma unroll
    for (int m = 0; m < 2; ++m) {
      float p0 = fmaxf(fmaxf(st[m][0][0], st[m][0][1]), st[m][0][2]);
      float p1 = fmaxf(fmaxf(st[m][0][3], st[m][1][0]), st[m][1][1]);
      float p2 = fmaxf(fmaxf(st[m][1][2], st[m][1][3]), st[m][2][0]);
      float p3 = fmaxf(fmaxf(st[m][2][1], st[m][2][2]), st[m][2][3]);
      float p4 = fmaxf(fmaxf(st[m][3][0], st[m][3][1]), st[m][3][2]);
      float pm = fmaxf(fmaxf(p0, p1), p2);
      pm = fmaxf(fmaxf(pm, p3), p4);
      pm = fmaxf(pm, st[m][3][3]);
      pm = fmaxf(pm, __shfl_xor(pm, 16));
      pm = fmaxf(pm, __shfl_xor(pm, 32));
      if (__any(pm > mrun[m] + 8.f)) {          // defer-max (T13)
        const float mn = fmaxf(mrun[m], pm);
        const float corr = exp2f(mrun[m] - mn);
        mrun[m] = mn;
#pragma unroll
        for (int j = 0; j < 4; ++j) osum[m][j] *= corr;
#pragma unroll
        for (int d = 0; d < 4; ++d)
#pragma unroll
          for (int j = 0; j < 4; ++j) o[m][d][j] *= corr;
      }
#pragma unroll
      for (int cf = 0; cf < 4; ++cf)
#pragma unroll
        for (int j = 0; j < 4; ++j)
          st[m][cf][j] = exp2f(st[m][cf][j] - mrun[m]);

      unsigned pk[4][2];
#pragma unroll
      for (int cf = 0; cf < 4; ++cf)
#pragma unroll
        for (int wp = 0; wp < 2; ++wp)
          pk[cf][wp] = cvt_pk_bf16(st[m][cf][2 * wp], st[m][cf][2 * wp + 1]);

      U8 a0, a1;
#pragma unroll
      for (int c = 0; c < 2; ++c) {
        const int src = lr + 16 * ((2 * lg + c) & 3);
#pragma unroll
        for (int wp = 0; wp < 2; ++wp) {
          const int v00 = __shfl((int)pk[0][wp], src);
          const int v01 = __shfl((int)pk[1][wp], src);
          const int v10 = __shfl((int)pk[2][wp], src);
          const int v11 = __shfl((int)pk[3][wp], src);
          a0.u[2 * c + wp] = (unsigned)((lg < 2) ? v00 : v01);
          a1.u[2 * c + wp] = (unsigned)((lg < 2) ? v10 : v11);
        }
      }
      paA[m] = a0.v;
      paB[m] = a1.v;
    }

    __builtin_amdgcn_s_setprio(1);
#pragma unroll
    for (int df = 0; df < 4; ++df) {
      const int vrow = df * 16 + lr;
      const int ch0 = lg ^ (vrow & 7);
      const int ch1 = (4 + lg) ^ (vrow & 7);
      const bf16x8 vf0 = *reinterpret_cast<const bf16x8*>(&Vs[cur][vrow * 64 + ch0 * 8]);
      const bf16x8 vf1 = *reinterpret_cast<const bf16x8*>(&Vs[cur][vrow * 64 + ch1 * 8]);
#pragma unroll
      for (int m = 0; m < 2; ++m) {
        o[m][df] = __builtin_amdgcn_mfma_f32_16x16x32_bf16(vf0, paA[m], o[m][df], 0, 0, 0);
        o[m][df] = __builtin_amdgcn_mfma_f32_16x16x32_bf16(vf1, paB[m], o[m][df], 0, 0, 0);
      }
    }
#pragma unroll
    for (int m = 0; m < 2; ++m) {
      osum[m] = __builtin_amdgcn_mfma_f32_16x16x32_bf16(ones, paA[m], osum[m], 0, 0, 0);
      osum[m] = __builtin_amdgcn_mfma_f32_16x16x32_bf16(ones, paB[m], osum[m], 0, 0, 0);
    }
    __builtin_amdgcn_s_setprio(0);

    asm volatile("s_waitcnt vmcnt(0)" ::: "memory");
    __syncthreads();
    cur ^= 1;
  }

#pragma unroll
  for (int m = 0; m < 2; ++m) {
    const float rdiv = 1.f / osum[m][0];
    const size_t rowbase = ((size_t)b * 2048 + r0 + m * 16 + lr) * 1024 + h * 64;
#pragma unroll
    for (int df = 0; df < 4; ++df) {
      uint2 s4;
      s4.x = cvt_pk_bf16(o[m][df][0] * rdiv, o[m][df][1] * rdiv);
      s4.y = cvt_pk_bf16(o[m][df][2] * rdiv, o[m][df][3] * rdiv);
      *reinterpret_cast<uint2*>(ctx + rowbase + df * 16 + lg * 4) = s4;
    }
  }
}

// ---------- launch ----------
extern "C" void kernel_launch(void* const* d_in, const int* in_sizes, int n_in,
                              void* d_out, int out_size, void* d_ws, size_t ws_size,
                              hipStream_t stream) {
  const float* x = (const float*)d_in[0];
  const int* mask = (const int*)d_in[1];
  const float* wq = (const float*)d_in[2];
  const float* bq = (const float*)d_in[3];
  const float* wk = (const float*)d_in[4];
  const float* bk = (const float*)d_in[5];
  const float* wv = (const float*)d_in[6];
  const float* bv = (const float*)d_in[7];
  const float* wo = (const float*)d_in[8];
  const float* bo = (const float*)d_in[9];
  const float* w1 = (const float*)d_in[10];
  const float* b1 = (const float*)d_in[11];
  const float* w2 = (const float*)d_in[12];
  const float* b2 = (const float*)d_in[13];
  const float* ln1a = (const float*)d_in[14];
  const float* ln1b = (const float*)d_in[15];
  const float* ln2a = (const float*)d_in[16];
  const float* ln2b = (const float*)d_in[17];

  const float SCL2 = 0.125f * 1.4426950408889634f;  // 1/sqrt(dk) * log2(e)
  const size_t LDS128_3 = 3 * (128 + 256) * 32 * sizeof(u16);  // 73728
  const size_t LDS128_4 = 4 * (128 + 256) * 32 * sizeof(u16);  // 98304

  hipFuncSetAttribute((const void*)&gemm8<3>,
                      hipFuncAttributeMaxDynamicSharedMemorySize, (int)LDS128_3);
  hipFuncSetAttribute((const void*)&gemm8<2>,
                      hipFuncAttributeMaxDynamicSharedMemorySize, (int)LDS128_3);
  hipFuncSetAttribute((const void*)&gemm9,
                      hipFuncAttributeMaxDynamicSharedMemorySize, (int)LDS128_4);

  char* ws = (char*)d_ws;
  const size_t MB = 1024ull * 1024ull;
  u16* WTQKV = (u16*)(ws + 0 * MB);    // [3072][1024] bf16, 6MB
  u16* WTO = (u16*)(ws + 6 * MB);      // 2MB
  u16* W1T = (u16*)(ws + 8 * MB);      // [4096][1024], 8MB
  u16* W2T = (u16*)(ws + 16 * MB);     // [1024][4096], 8MB
  float* BQKV = (float*)(ws + 24 * MB);              // 12KB
  float* MBIAS = (float*)(ws + 24 * MB + 65536);     // 32KB
  int* FLAGS = (int*)(ws + 24 * MB + 131072);        // 16B
  u16* QKV = (u16*)(ws + 25 * MB);     // [8192][3072] bf16 (Q,K cols used), 48MB (25-73)
  u16* VT = (u16*)(ws + 73 * MB);      // [4][1024][2048] bf16, 16MB (73-89)
  u16* XN = (u16*)(ws + 89 * MB);      // 16MB (89-105); dead after QKV gemm
  u16* CTX = (u16*)(ws + 105 * MB);    // 16MB (105-121)
  float* X2 = (float*)(ws + 25 * MB);  // 32MB (25-57), overwrites QKV after attn
  u16* XN2 = (u16*)(ws + 57 * MB);     // 16MB (57-73)
  u16* H1 = (u16*)(ws + 73 * MB);      // [8192][4096] bf16, 64MB (73-137)

  dim3 bt(32, 8);
  wcvt_t<<<dim3(32, 32), bt, 0, stream>>>(wq, WTQKV, 1024, 1024, SCL2);
  wcvt_t<<<dim3(32, 32), bt, 0, stream>>>(wk, WTQKV + 1024 * 1024, 1024, 1024, 1.f);
  wcvt_t<<<dim3(32, 32), bt, 0, stream>>>(wv, WTQKV + 2048 * 1024, 1024, 1024, 1.f);
  wcvt_t<<<dim3(32, 32), bt, 0, stream>>>(wo, WTO, 1024, 1024, 1.f);
  wcvt_t<<<dim3(128, 32), bt, 0, stream>>>(w1, W1T, 1024, 4096, 1.f);
  wcvt_t<<<dim3(32, 128), bt, 0, stream>>>(w2, W2T, 4096, 1024, 1.f);
  pack_bias<<<dim3(12), 256, 0, stream>>>(bq, bk, bv, BQKV, SCL2);
  mk_mbias<<<dim3(4), 256, 0, stream>>>(mask, MBIAS, FLAGS);

  ln_kernel<<<8192, 256, 0, stream>>>(x, XN, ln1a, ln1b);
  // fused QKV projection (128x256 tiles, ring-3); V written transposed to VT
  gemm8<3><<<dim3(12, 64), 512, LDS128_3, stream>>>(XN, WTQKV, BQKV, nullptr, QKV, VT, 8192, 3072, 1024);
  attn_fwd9<<<dim3(8, 64), 512, 0, stream>>>(QKV, VT, MBIAS, FLAGS, CTX);
  // O-proj (1 block/CU -> ring-4, 2 tiles/barrier)
  gemm9<<<dim3(4, 64), 512, LDS128_4, stream>>>(CTX, WTO, bo, x, X2, 8192, 1024, 1024);
  ln_kernel<<<8192, 256, 0, stream>>>(X2, XN2, ln2a, ln2b);
  // FFN1 (128x256 tiles, ring-3, 2 blocks/CU)
  gemm8<2><<<dim3(16, 64), 512, LDS128_3, stream>>>(XN2, W1T, b1, nullptr, H1, nullptr, 8192, 4096, 1024);
  // FFN2 (1 block/CU -> ring-4, 2 tiles/barrier)
  gemm9<<<dim3(4, 64), 512, LDS128_4, stream>>>(H1, W2T, b2, X2, (float*)d_out, 8192, 1024, 4096);
}

// Round 18
// 433.063 us; speedup vs baseline: 1.0423x; 1.0423x over previous
//
#include <hip/hip_runtime.h>

typedef unsigned short u16;
typedef __bf16 bf16x8 __attribute__((ext_vector_type(8)));
typedef float f32x4 __attribute__((ext_vector_type(4)));

// ---------- helpers ----------
__device__ __forceinline__ u16 f2bf(float f) {
  unsigned u = __builtin_bit_cast(unsigned, f);
  unsigned lsb = (u >> 16) & 1u;
  u += 0x7fffu + lsb;                 // round-to-nearest-even
  return (u16)(u >> 16);
}

// D.lo = bf16(lo), D.hi = bf16(hi) — single VALU op
__device__ __forceinline__ unsigned cvt_pk_bf16(float lo, float hi) {
  unsigned r;
  asm("v_cvt_pk_bf16_f32 %0, %1, %2" : "=v"(r) : "v"(lo), "v"(hi));
  return r;
}

__device__ __forceinline__ void gld_lds16(const u16* g, u16* l) {
  __builtin_amdgcn_global_load_lds(
      (__attribute__((address_space(1))) void*)g,
      (__attribute__((address_space(3))) void*)l, 16, 0, 0);
}

// ---------- LayerNorm ----------
__global__ __launch_bounds__(256) void ln_kernel(
    const float* __restrict__ x, u16* __restrict__ out,
    const float* __restrict__ alpha_p, const float* __restrict__ beta_p) {
  const int row = blockIdx.x;
  const int t = threadIdx.x;
  const float4 v = reinterpret_cast<const float4*>(x + (size_t)row * 1024)[t];
  float s = v.x + v.y + v.z + v.w;
  float sq = v.x * v.x + v.y * v.y + v.z * v.z + v.w * v.w;
#pragma unroll
  for (int off = 32; off > 0; off >>= 1) {
    s += __shfl_down(s, off);
    sq += __shfl_down(sq, off);
  }
  __shared__ float red[8];
  const int w = t >> 6;
  if ((t & 63) == 0) { red[w] = s; red[4 + w] = sq; }
  __syncthreads();
  const float ts = red[0] + red[1] + red[2] + red[3];
  const float tq = red[4] + red[5] + red[6] + red[7];
  const float mean = ts * (1.0f / 1024.0f);
  float var = (tq - ts * mean) * (1.0f / 1023.0f);
  var = fmaxf(var, 0.0f);
  const float rden = 1.0f / (sqrtf(var) + 1e-5f);
  const float a = alpha_p[0], bb = beta_p[0];
  uint2 ov;
  ov.x = cvt_pk_bf16(a * (v.x - mean) * rden + bb, a * (v.y - mean) * rden + bb);
  ov.y = cvt_pk_bf16(a * (v.z - mean) * rden + bb, a * (v.w - mean) * rden + bb);
  reinterpret_cast<uint2*>(out + (size_t)row * 1024)[t] = ov;
}

// ---------- weight convert fp32 [K][N] -> bf16 transposed [N][K], optional scale ----------
__global__ __launch_bounds__(256) void wcvt_t(
    const float* __restrict__ w, u16* __restrict__ wt, int K, int N, float scale) {
  __shared__ float tile[32][33];
  const int n0 = blockIdx.x * 32, k0 = blockIdx.y * 32;
  const int tx = threadIdx.x, ty = threadIdx.y;
#pragma unroll
  for (int i = 0; i < 4; ++i)
    tile[ty + i * 8][tx] = w[(size_t)(k0 + ty + i * 8) * N + n0 + tx];
  __syncthreads();
#pragma unroll
  for (int i = 0; i < 4; ++i)
    wt[(size_t)(n0 + ty + i * 8) * K + k0 + tx] = f2bf(tile[tx][ty + i * 8] * scale);
}

// ---------- fused 4x 1024x1024 weight convert (z = which weight) ----------
__global__ __launch_bounds__(256) void wcvt_t4(
    const float* __restrict__ w0, const float* __restrict__ w1,
    const float* __restrict__ w2, const float* __restrict__ w3,
    u16* __restrict__ dqkv, u16* __restrict__ dwo, float qscale) {
  __shared__ float tile[32][33];
  const int z = blockIdx.z;
  const float* w = (z == 0) ? w0 : (z == 1) ? w1 : (z == 2) ? w2 : w3;
  u16* wt = (z < 3) ? (dqkv + (size_t)z * 1024 * 1024) : dwo;
  const float scale = (z == 0) ? qscale : 1.f;
  const int n0 = blockIdx.x * 32, k0 = blockIdx.y * 32;
  const int tx = threadIdx.x, ty = threadIdx.y;
#pragma unroll
  for (int i = 0; i < 4; ++i)
    tile[ty + i * 8][tx] = w[(size_t)(k0 + ty + i * 8) * 1024 + n0 + tx];
  __syncthreads();
#pragma unroll
  for (int i = 0; i < 4; ++i)
    wt[(size_t)(n0 + ty + i * 8) * 1024 + k0 + tx] = f2bf(tile[tx][ty + i * 8] * scale);
}

// ---------- bias concat (bq pre-scaled) ----------
__global__ __launch_bounds__(256) void pack_bias(
    const float* __restrict__ a, const float* __restrict__ b,
    const float* __restrict__ c, float* __restrict__ o, float qscale) {
  const int i = blockIdx.x * 256 + threadIdx.x;
  o[i] = (i < 1024) ? a[i] * qscale : ((i < 2048) ? b[i - 1024] : c[i - 2048]);
}

// ---------- mask bias (log2 domain) + per-batch all-live flag ----------
__global__ __launch_bounds__(256) void mk_mbias(
    const int* __restrict__ mask, float* __restrict__ mb, int* __restrict__ flags) {
  const int b = blockIdx.x, t = threadIdx.x;
  __shared__ int bad;
  if (t == 0) bad = 0;
  __syncthreads();
  int loc = 0;
#pragma unroll
  for (int i = 0; i < 8; ++i) {
    const int idx = b * 2048 + t * 8 + i;
    const int mv = mask[idx];
    mb[idx] = mv ? 0.f : -1.4427e9f;
    loc |= (mv == 0);
  }
  if (loc) atomicOr(&bad, 1);
  __syncthreads();
  if (t == 0) flags[b] = !bad;
}

// ---------- GEMM: ring-DEPTH, counted vmcnt, 512 threads, BM=128/BN=256 ----------
// EPI 1: f32 out = acc+bias+res.  EPI 2: bf16 relu out.
// EPI 3: QKV — cols<2048 bf16 to Cout; cols>=2048 transposed to vt [B][1024][2048].
template <int EPI, int DEPTH>
__global__ __launch_bounds__(512, 4) void gemm8(
    const u16* __restrict__ A, const u16* __restrict__ Bt,
    const float* __restrict__ bias, const float* __restrict__ res,
    void* __restrict__ Cout, u16* __restrict__ vt, int M, int N, int K) {
  constexpr int BM = 128, BN = 256;
  constexpr int VMC = 3;
  constexpr int PD = DEPTH - 1;
  constexpr int MF = 4;
  extern __shared__ u16 smem[];             // [DEPTH][BM*32] A + [DEPTH][BN*32] B
  u16* Asb = smem;
  u16* Bsb = smem + DEPTH * BM * 32;

  const int tid = threadIdx.x;
  const int l = tid & 63;
  const int w = tid >> 6;
  const int wr = w >> 2, wc = w & 3;
  const int gx = gridDim.x;
  int id = blockIdx.y * gx + blockIdx.x;
  const int nwg = gx * gridDim.y;
  id = (id & 7) * (nwg >> 3) + (id >> 3);
  const int n0 = (id % gx) * BN;
  const int m0 = (id / gx) * BM;
  const int lr = l & 15, lg = l >> 4;
  const int koff = (lg ^ ((lr >> 1) & 3)) * 8;

  f32x4 acc[MF][4];
#pragma unroll
  for (int i = 0; i < MF; ++i)
#pragma unroll
    for (int j = 0; j < 4; ++j) acc[i][j] = f32x4{0.f, 0.f, 0.f, 0.f};

  const u16* aSrc;
  int aOff;
  {
    const int ci = tid;
    const int row = ci >> 2, c = ci & 3;
    const int sc = c ^ ((row >> 1) & 3);
    aSrc = A + (size_t)(m0 + row) * K + sc * 8;
    aOff = ci * 8;
  }
  const u16* bSrc[2];
  int bOff[2];
#pragma unroll
  for (int i = 0; i < 2; ++i) {
    const int ci = tid + i * 512;
    const int row = ci >> 2, c = ci & 3;
    const int sc = c ^ ((row >> 1) & 3);
    bSrc[i] = Bt + (size_t)(n0 + row) * K + sc * 8;
    bOff[i] = ci * 8;
  }

  const int NT = K >> 5;
  // prologue: stage tiles 0..PD-1
#pragma unroll
  for (int s = 0; s < PD; ++s) {
    gld_lds16(aSrc + s * 32, Asb + s * BM * 32 + aOff);
#pragma unroll
    for (int i = 0; i < 2; ++i) gld_lds16(bSrc[i] + s * 32, Bsb + s * BN * 32 + bOff[i]);
  }
  if constexpr ((PD - 1) * VMC == 3) asm volatile("s_waitcnt vmcnt(3)" ::: "memory");
  else asm volatile("s_waitcnt vmcnt(6)" ::: "memory");
  __builtin_amdgcn_s_barrier();

  int cur = 0;
  for (int t = 0; t < NT; ++t) {
    if (t + PD < NT) {
      int nx = cur + PD;
      if (nx >= DEPTH) nx -= DEPTH;
      const int ko = (t + PD) * 32;
      gld_lds16(aSrc + ko, Asb + nx * BM * 32 + aOff);
#pragma unroll
      for (int i = 0; i < 2; ++i) gld_lds16(bSrc[i] + ko, Bsb + nx * BN * 32 + bOff[i]);
    }
    const u16* Ab = Asb + cur * BM * 32;
    const u16* Bb = Bsb + cur * BN * 32;
    bf16x8 a[MF], b[4];
#pragma unroll
    for (int mf = 0; mf < MF; ++mf)
      a[mf] = *reinterpret_cast<const bf16x8*>(&Ab[(wr * (BM / 2) + mf * 16 + lr) * 32 + koff]);
#pragma unroll
    for (int nf = 0; nf < 4; ++nf)
      b[nf] = *reinterpret_cast<const bf16x8*>(&Bb[(wc * 64 + nf * 16 + lr) * 32 + koff]);
    __builtin_amdgcn_s_setprio(1);
#pragma unroll
    for (int mf = 0; mf < MF; ++mf)
#pragma unroll
      for (int nf = 0; nf < 4; ++nf)
        acc[mf][nf] = __builtin_amdgcn_mfma_f32_16x16x32_bf16(a[mf], b[nf], acc[mf][nf], 0, 0, 0);
    __builtin_amdgcn_s_setprio(0);
    {
      const int ahead = NT - 2 - t;
      if constexpr (PD == 2) {
        if (ahead >= 1) asm volatile("s_waitcnt vmcnt(3)" ::: "memory");
        else asm volatile("s_waitcnt vmcnt(0)" ::: "memory");
      } else {  // PD == 3
        if (ahead >= 2) asm volatile("s_waitcnt vmcnt(6)" ::: "memory");
        else if (ahead == 1) asm volatile("s_waitcnt vmcnt(3)" ::: "memory");
        else asm volatile("s_waitcnt vmcnt(0)" ::: "memory");
      }
    }
    __builtin_amdgcn_s_barrier();
    cur = (cur + 1 >= DEPTH) ? 0 : cur + 1;
  }

  if (EPI == 3 && n0 >= 2048) {
#pragma unroll
    for (int mf = 0; mf < MF; ++mf) {
#pragma unroll
      for (int nf = 0; nf < 4; ++nf) {
        const int col = n0 + wc * 64 + nf * 16 + lr;
        const float bv = bias[col];
        const int row0 = m0 + wr * (BM / 2) + mf * 16 + lg * 4;
        const int bb = row0 >> 11, s0 = row0 & 2047;
        const int d = col - 2048;
        uint2 pv;
        pv.x = cvt_pk_bf16(acc[mf][nf][0] + bv, acc[mf][nf][1] + bv);
        pv.y = cvt_pk_bf16(acc[mf][nf][2] + bv, acc[mf][nf][3] + bv);
        *reinterpret_cast<uint2*>(vt + ((size_t)bb * 1024 + d) * 2048 + s0) = pv;
      }
    }
    return;
  }

#pragma unroll
  for (int mf = 0; mf < MF; ++mf) {
#pragma unroll
    for (int nf = 0; nf < 4; ++nf) {
      const int col = n0 + wc * 64 + nf * 16 + lr;
      const float bv = bias[col];
#pragma unroll
      for (int j = 0; j < 4; ++j) {
        const int row = m0 + wr * (BM / 2) + mf * 16 + lg * 4 + j;
        const size_t idx = (size_t)row * N + col;
        const float vv = acc[mf][nf][j] + bv;
        if (EPI == 1)
          ((float*)Cout)[idx] = vv + res[idx];
        else if (EPI == 2)
          ((u16*)Cout)[idx] = f2bf(fmaxf(vv, 0.f));
        else
          ((u16*)Cout)[idx] = f2bf(vv);
      }
    }
  }
}

// ---------- flash attention: 8 waves, 256 q-rows/block, dbuf K/V, 32KB LDS ----------
// qkv: [B*S][3072] bf16 (Q pre-scaled to exp2 domain at +0, K at +1024).
// vt: [B][1024][2048] bf16. mbias: [B][2048] f32 (log2 domain). flags: [B] all-live.
// grid MUST be dim3(8, 64): head-local XCD swizzle keeps each head's K/V in one XCD's L2.
__global__ __launch_bounds__(512, 4) void attn_fwd9(
    const u16* __restrict__ qkv, const u16* __restrict__ vt,
    const float* __restrict__ mbias, const int* __restrict__ flags,
    u16* __restrict__ ctx) {
  __shared__ u16 Ks[2][64 * 64];
  __shared__ u16 Vs[2][64 * 64];
  const int tid = threadIdx.x;
  const int l = tid & 63;
  const int w = tid >> 6;                   // 0..7
  const int p = blockIdx.y * 8 + blockIdx.x;
  const int idx = p >> 3;                   // 0..63
  const int bh = (p & 7) * 8 + (idx >> 3);  // 0..63
  const int qx = idx & 7;                   // 0..7
  const int b = bh >> 4, h = bh & 15;
  const int r0 = qx * 256 + w * 32;
  const int lr = l & 15, lg = l >> 4;

  const u16* qb = qkv + (size_t)b * 2048 * 3072 + h * 64;
  const u16* kp = qb + 1024;
  const u16* vb = vt + ((size_t)b * 1024 + h * 64) * 2048;
  const float* mb = mbias + (size_t)b * 2048;
  const int allLive = flags[b];

  bf16x8 qf[2][2];
#pragma unroll
  for (int m = 0; m < 2; ++m)
#pragma unroll
    for (int ks = 0; ks < 2; ++ks)
      qf[m][ks] = *reinterpret_cast<const bf16x8*>(
          qb + (size_t)(r0 + m * 16 + lr) * 3072 + ks * 32 + lg * 8);

  bf16x8 ones;
#pragma unroll
  for (int e = 0; e < 8; ++e) ones[e] = (__bf16)1.0f;

  float mrun[2] = {-1e30f, -1e30f};
  f32x4 osum[2];
  f32x4 o[2][4];
#pragma unroll
  for (int m = 0; m < 2; ++m) {
    osum[m] = f32x4{0.f, 0.f, 0.f, 0.f};
#pragma unroll
    for (int d = 0; d < 4; ++d) o[m][d] = f32x4{0.f, 0.f, 0.f, 0.f};
  }

  const int srow = tid >> 3, scc = tid & 7;
  const int ssc = scc ^ (srow & 7);
  const u16* kS = kp + (size_t)srow * 3072 + ssc * 8;
  const u16* vS = vb + (size_t)srow * 2048 + ssc * 8;
  gld_lds16(kS, &Ks[0][tid * 8]);
  gld_lds16(vS, &Vs[0][tid * 8]);
  asm volatile("s_waitcnt vmcnt(0)" ::: "memory");
  __syncthreads();

  union U8 { unsigned u[4]; bf16x8 v; };

  int cur = 0;
  for (int t = 0; t < 32; ++t) {
    const int kb0 = t * 64;
    if (t + 1 < 32) {
      const int nb = kb0 + 64;
      gld_lds16(kS + (size_t)nb * 3072, &Ks[cur ^ 1][tid * 8]);
      gld_lds16(vS + nb, &Vs[cur ^ 1][tid * 8]);
    }

    f32x4 st[2][4];
    __builtin_amdgcn_s_setprio(1);
#pragma unroll
    for (int cf = 0; cf < 4; ++cf) {
      const int krow = cf * 16 + lr;
      const int ch0 = lg ^ (krow & 7);
      const int ch1 = (4 + lg) ^ (krow & 7);
      const bf16x8 kf0 = *reinterpret_cast<const bf16x8*>(&Ks[cur][krow * 64 + ch0 * 8]);
      const bf16x8 kf1 = *reinterpret_cast<const bf16x8*>(&Ks[cur][krow * 64 + ch1 * 8]);
#pragma unroll
      for (int m = 0; m < 2; ++m) {
        f32x4 acc = __builtin_amdgcn_mfma_f32_16x16x32_bf16(kf0, qf[m][0],
                                                            f32x4{0.f, 0.f, 0.f, 0.f}, 0, 0, 0);
        st[m][cf] = __builtin_amdgcn_mfma_f32_16x16x32_bf16(kf1, qf[m][1], acc, 0, 0, 0);
      }
    }
    __builtin_amdgcn_s_setprio(0);

    if (!allLive) {
#pragma unroll
      for (int cf = 0; cf < 4; ++cf) {
        const float4 m4 = *reinterpret_cast<const float4*>(mb + kb0 + cf * 16 + lg * 4);
#pragma unroll
        for (int m = 0; m < 2; ++m) {
          st[m][cf][0] += m4.x;
          st[m][cf][1] += m4.y;
          st[m][cf][2] += m4.z;
          st[m][cf][3] += m4.w;
        }
      }
    }

    bf16x8 paA[2], paB[2];
#pragma unroll
    for (int m = 0; m < 2; ++m) {
      float p0 = fmaxf(fmaxf(st[m][0][0], st[m][0][1]), st[m][0][2]);
      float p1 = fmaxf(fmaxf(st[m][0][3], st[m][1][0]), st[m][1][1]);
      float p2 = fmaxf(fmaxf(st[m][1][2], st[m][1][3]), st[m][2][0]);
      float p3 = fmaxf(fmaxf(st[m][2][1], st[m][2][2]), st[m][2][3]);
      float p4 = fmaxf(fmaxf(st[m][3][0], st[m][3][1]), st[m][3][2]);
      float pm = fmaxf(fmaxf(p0, p1), p2);
      pm = fmaxf(fmaxf(pm, p3), p4);
      pm = fmaxf(pm, st[m][3][3]);
      pm = fmaxf(pm, __shfl_xor(pm, 16));
      pm = fmaxf(pm, __shfl_xor(pm, 32));
      if (__any(pm > mrun[m] + 8.f)) {          // defer-max (T13)
        const float mn = fmaxf(mrun[m], pm);
        const float corr = exp2f(mrun[m] - mn);
        mrun[m] = mn;
#pragma unroll
        for (int j = 0; j < 4; ++j) osum[m][j] *= corr;
#pragma unroll
        for (int d = 0; d < 4; ++d)
#pragma unroll
          for (int j = 0; j < 4; ++j) o[m][d][j] *= corr;
      }
#pragma unroll
      for (int cf = 0; cf < 4; ++cf)
#pragma unroll
        for (int j = 0; j < 4; ++j)
          st[m][cf][j] = exp2f(st[m][cf][j] - mrun[m]);

      unsigned pk[4][2];
#pragma unroll
      for (int cf = 0; cf < 4; ++cf)
#pragma unroll
        for (int wp = 0; wp < 2; ++wp)
          pk[cf][wp] = cvt_pk_bf16(st[m][cf][2 * wp], st[m][cf][2 * wp + 1]);

      U8 a0, a1;
#pragma unroll
      for (int c = 0; c < 2; ++c) {
        const int src = lr + 16 * ((2 * lg + c) & 3);
#pragma unroll
        for (int wp = 0; wp < 2; ++wp) {
          const int v00 = __shfl((int)pk[0][wp], src);
          const int v01 = __shfl((int)pk[1][wp], src);
          const int v10 = __shfl((int)pk[2][wp], src);
          const int v11 = __shfl((int)pk[3][wp], src);
          a0.u[2 * c + wp] = (unsigned)((lg < 2) ? v00 : v01);
          a1.u[2 * c + wp] = (unsigned)((lg < 2) ? v10 : v11);
        }
      }
      paA[m] = a0.v;
      paB[m] = a1.v;
    }

    __builtin_amdgcn_s_setprio(1);
#pragma unroll
    for (int df = 0; df < 4; ++df) {
      const int vrow = df * 16 + lr;
      const int ch0 = lg ^ (vrow & 7);
      const int ch1 = (4 + lg) ^ (vrow & 7);
      const bf16x8 vf0 = *reinterpret_cast<const bf16x8*>(&Vs[cur][vrow * 64 + ch0 * 8]);
      const bf16x8 vf1 = *reinterpret_cast<const bf16x8*>(&Vs[cur][vrow * 64 + ch1 * 8]);
#pragma unroll
      for (int m = 0; m < 2; ++m) {
        o[m][df] = __builtin_amdgcn_mfma_f32_16x16x32_bf16(vf0, paA[m], o[m][df], 0, 0, 0);
        o[m][df] = __builtin_amdgcn_mfma_f32_16x16x32_bf16(vf1, paB[m], o[m][df], 0, 0, 0);
      }
    }
#pragma unroll
    for (int m = 0; m < 2; ++m) {
      osum[m] = __builtin_amdgcn_mfma_f32_16x16x32_bf16(ones, paA[m], osum[m], 0, 0, 0);
      osum[m] = __builtin_amdgcn_mfma_f32_16x16x32_bf16(ones, paB[m], osum[m], 0, 0, 0);
    }
    __builtin_amdgcn_s_setprio(0);

    asm volatile("s_waitcnt vmcnt(0)" ::: "memory");
    __syncthreads();
    cur ^= 1;
  }

#pragma unroll
  for (int m = 0; m < 2; ++m) {
    const float rdiv = 1.f / osum[m][0];
    const size_t rowbase = ((size_t)b * 2048 + r0 + m * 16 + lr) * 1024 + h * 64;
#pragma unroll
    for (int df = 0; df < 4; ++df) {
      uint2 s4;
      s4.x = cvt_pk_bf16(o[m][df][0] * rdiv, o[m][df][1] * rdiv);
      s4.y = cvt_pk_bf16(o[m][df][2] * rdiv, o[m][df][3] * rdiv);
      *reinterpret_cast<uint2*>(ctx + rowbase + df * 16 + lg * 4) = s4;
    }
  }
}

// ---------- launch ----------
extern "C" void kernel_launch(void* const* d_in, const int* in_sizes, int n_in,
                              void* d_out, int out_size, void* d_ws, size_t ws_size,
                              hipStream_t stream) {
  const float* x = (const float*)d_in[0];
  const int* mask = (const int*)d_in[1];
  const float* wq = (const float*)d_in[2];
  const float* bq = (const float*)d_in[3];
  const float* wk = (const float*)d_in[4];
  const float* bk = (const float*)d_in[5];
  const float* wv = (const float*)d_in[6];
  const float* bv = (const float*)d_in[7];
  const float* wo = (const float*)d_in[8];
  const float* bo = (const float*)d_in[9];
  const float* w1 = (const float*)d_in[10];
  const float* b1 = (const float*)d_in[11];
  const float* w2 = (const float*)d_in[12];
  const float* b2 = (const float*)d_in[13];
  const float* ln1a = (const float*)d_in[14];
  const float* ln1b = (const float*)d_in[15];
  const float* ln2a = (const float*)d_in[16];
  const float* ln2b = (const float*)d_in[17];

  const float SCL2 = 0.125f * 1.4426950408889634f;  // 1/sqrt(dk) * log2(e)
  const size_t LDS128_3 = 3 * (128 + 256) * 32 * sizeof(u16);  // 73728
  const size_t LDS128_4 = 4 * (128 + 256) * 32 * sizeof(u16);  // 98304

  (void)hipFuncSetAttribute((const void*)&gemm8<3, 3>,
                            hipFuncAttributeMaxDynamicSharedMemorySize, (int)LDS128_3);
  (void)hipFuncSetAttribute((const void*)&gemm8<2, 3>,
                            hipFuncAttributeMaxDynamicSharedMemorySize, (int)LDS128_3);
  (void)hipFuncSetAttribute((const void*)&gemm8<1, 4>,
                            hipFuncAttributeMaxDynamicSharedMemorySize, (int)LDS128_4);

  char* ws = (char*)d_ws;
  const size_t MB = 1024ull * 1024ull;
  u16* WTQKV = (u16*)(ws + 0 * MB);    // [3072][1024] bf16, 6MB
  u16* WTO = (u16*)(ws + 6 * MB);      // 2MB
  u16* W1T = (u16*)(ws + 8 * MB);      // [4096][1024], 8MB
  u16* W2T = (u16*)(ws + 16 * MB);     // [1024][4096], 8MB
  float* BQKV = (float*)(ws + 24 * MB);              // 12KB
  float* MBIAS = (float*)(ws + 24 * MB + 65536);     // 32KB
  int* FLAGS = (int*)(ws + 24 * MB + 131072);        // 16B
  u16* QKV = (u16*)(ws + 25 * MB);     // [8192][3072] bf16 (Q,K cols used), 48MB (25-73)
  u16* VT = (u16*)(ws + 73 * MB);      // [4][1024][2048] bf16, 16MB (73-89)
  u16* XN = (u16*)(ws + 89 * MB);      // 16MB (89-105); dead after QKV gemm
  u16* CTX = (u16*)(ws + 105 * MB);    // 16MB (105-121)
  float* X2 = (float*)(ws + 25 * MB);  // 32MB (25-57), overwrites QKV after attn
  u16* XN2 = (u16*)(ws + 57 * MB);     // 16MB (57-73)
  u16* H1 = (u16*)(ws + 73 * MB);      // [8192][4096] bf16, 64MB (73-137)

  dim3 bt(32, 8);
  // fused 4x 1024^2 weight converts (wq scaled), then the two FFN weights
  wcvt_t4<<<dim3(32, 32, 4), bt, 0, stream>>>(wq, wk, wv, wo, WTQKV, WTO, SCL2);
  wcvt_t<<<dim3(128, 32), bt, 0, stream>>>(w1, W1T, 1024, 4096, 1.f);
  wcvt_t<<<dim3(32, 128), bt, 0, stream>>>(w2, W2T, 4096, 1024, 1.f);
  pack_bias<<<dim3(12), 256, 0, stream>>>(bq, bk, bv, BQKV, SCL2);
  mk_mbias<<<dim3(4), 256, 0, stream>>>(mask, MBIAS, FLAGS);

  ln_kernel<<<8192, 256, 0, stream>>>(x, XN, ln1a, ln1b);
  // fused QKV projection (128x256 tiles, ring-3); V written transposed to VT
  gemm8<3, 3><<<dim3(12, 64), 512, LDS128_3, stream>>>(XN, WTQKV, BQKV, nullptr, QKV, VT, 8192, 3072, 1024);
  attn_fwd9<<<dim3(8, 64), 512, 0, stream>>>(QKV, VT, MBIAS, FLAGS, CTX);
  // O-proj (1 block/CU -> ring-4 depth-3 prefetch)
  gemm8<1, 4><<<dim3(4, 64), 512, LDS128_4, stream>>>(CTX, WTO, bo, x, X2, nullptr, 8192, 1024, 1024);
  ln_kernel<<<8192, 256, 0, stream>>>(X2, XN2, ln2a, ln2b);
  // FFN1 (128x256 tiles, ring-3, 2 blocks/CU)
  gemm8<2, 3><<<dim3(16, 64), 512, LDS128_3, stream>>>(XN2, W1T, b1, nullptr, H1, nullptr, 8192, 4096, 1024);
  // FFN2 (1 block/CU -> ring-4)
  gemm8<1, 4><<<dim3(4, 64), 512, LDS128_4, stream>>>(H1, W2T, b2, X2, (float*)d_out, nullptr, 8192, 1024, 4096);
}

// Round 19
// 427.853 us; speedup vs baseline: 1.0549x; 1.0122x over previous
//
#include <hip/hip_runtime.h>

typedef unsigned short u16;
typedef __bf16 bf16x8 __attribute__((ext_vector_type(8)));
typedef float f32x4 __attribute__((ext_vector_type(4)));

// ---------- helpers ----------
__device__ __forceinline__ u16 f2bf(float f) {
  unsigned u = __builtin_bit_cast(unsigned, f);
  unsigned lsb = (u >> 16) & 1u;
  u += 0x7fffu + lsb;                 // round-to-nearest-even
  return (u16)(u >> 16);
}

__device__ __forceinline__ float bf2f(u16 b) {
  return __builtin_bit_cast(float, (unsigned)b << 16);
}

// D.lo = bf16(lo), D.hi = bf16(hi) — single VALU op
__device__ __forceinline__ unsigned cvt_pk_bf16(float lo, float hi) {
  unsigned r;
  asm("v_cvt_pk_bf16_f32 %0, %1, %2" : "=v"(r) : "v"(lo), "v"(hi));
  return r;
}

__device__ __forceinline__ void gld_lds16(const u16* g, u16* l) {
  __builtin_amdgcn_global_load_lds(
      (__attribute__((address_space(1))) void*)g,
      (__attribute__((address_space(3))) void*)l, 16, 0, 0);
}

// ---------- LayerNorm (f32 input) ----------
__global__ __launch_bounds__(256) void ln_kernel(
    const float* __restrict__ x, u16* __restrict__ out,
    const float* __restrict__ alpha_p, const float* __restrict__ beta_p) {
  const int row = blockIdx.x;
  const int t = threadIdx.x;
  const float4 v = reinterpret_cast<const float4*>(x + (size_t)row * 1024)[t];
  float s = v.x + v.y + v.z + v.w;
  float sq = v.x * v.x + v.y * v.y + v.z * v.z + v.w * v.w;
#pragma unroll
  for (int off = 32; off > 0; off >>= 1) {
    s += __shfl_down(s, off);
    sq += __shfl_down(sq, off);
  }
  __shared__ float red[8];
  const int w = t >> 6;
  if ((t & 63) == 0) { red[w] = s; red[4 + w] = sq; }
  __syncthreads();
  const float ts = red[0] + red[1] + red[2] + red[3];
  const float tq = red[4] + red[5] + red[6] + red[7];
  const float mean = ts * (1.0f / 1024.0f);
  float var = (tq - ts * mean) * (1.0f / 1023.0f);
  var = fmaxf(var, 0.0f);
  const float rden = 1.0f / (sqrtf(var) + 1e-5f);
  const float a = alpha_p[0], bb = beta_p[0];
  uint2 ov;
  ov.x = cvt_pk_bf16(a * (v.x - mean) * rden + bb, a * (v.y - mean) * rden + bb);
  ov.y = cvt_pk_bf16(a * (v.z - mean) * rden + bb, a * (v.w - mean) * rden + bb);
  reinterpret_cast<uint2*>(out + (size_t)row * 1024)[t] = ov;
}

// ---------- LayerNorm (bf16 input) ----------
__global__ __launch_bounds__(256) void ln_kernel_bf(
    const u16* __restrict__ x, u16* __restrict__ out,
    const float* __restrict__ alpha_p, const float* __restrict__ beta_p) {
  const int row = blockIdx.x;
  const int t = threadIdx.x;
  const uint2 raw = reinterpret_cast<const uint2*>(x + (size_t)row * 1024)[t];
  float v0 = bf2f((u16)(raw.x & 0xffff)), v1 = bf2f((u16)(raw.x >> 16));
  float v2 = bf2f((u16)(raw.y & 0xffff)), v3 = bf2f((u16)(raw.y >> 16));
  float s = v0 + v1 + v2 + v3;
  float sq = v0 * v0 + v1 * v1 + v2 * v2 + v3 * v3;
#pragma unroll
  for (int off = 32; off > 0; off >>= 1) {
    s += __shfl_down(s, off);
    sq += __shfl_down(sq, off);
  }
  __shared__ float red[8];
  const int w = t >> 6;
  if ((t & 63) == 0) { red[w] = s; red[4 + w] = sq; }
  __syncthreads();
  const float ts = red[0] + red[1] + red[2] + red[3];
  const float tq = red[4] + red[5] + red[6] + red[7];
  const float mean = ts * (1.0f / 1024.0f);
  float var = (tq - ts * mean) * (1.0f / 1023.0f);
  var = fmaxf(var, 0.0f);
  const float rden = 1.0f / (sqrtf(var) + 1e-5f);
  const float a = alpha_p[0], bb = beta_p[0];
  uint2 ov;
  ov.x = cvt_pk_bf16(a * (v0 - mean) * rden + bb, a * (v1 - mean) * rden + bb);
  ov.y = cvt_pk_bf16(a * (v2 - mean) * rden + bb, a * (v3 - mean) * rden + bb);
  reinterpret_cast<uint2*>(out + (size_t)row * 1024)[t] = ov;
}

// ---------- weight convert fp32 [K][N] -> bf16 transposed [N][K], optional scale ----------
__global__ __launch_bounds__(256) void wcvt_t(
    const float* __restrict__ w, u16* __restrict__ wt, int K, int N, float scale) {
  __shared__ float tile[32][33];
  const int n0 = blockIdx.x * 32, k0 = blockIdx.y * 32;
  const int tx = threadIdx.x, ty = threadIdx.y;
#pragma unroll
  for (int i = 0; i < 4; ++i)
    tile[ty + i * 8][tx] = w[(size_t)(k0 + ty + i * 8) * N + n0 + tx];
  __syncthreads();
#pragma unroll
  for (int i = 0; i < 4; ++i)
    wt[(size_t)(n0 + ty + i * 8) * K + k0 + tx] = f2bf(tile[tx][ty + i * 8] * scale);
}

// ---------- fused 4x 1024x1024 weight convert (z = which weight) ----------
__global__ __launch_bounds__(256) void wcvt_t4(
    const float* __restrict__ w0, const float* __restrict__ w1,
    const float* __restrict__ w2, const float* __restrict__ w3,
    u16* __restrict__ dqkv, u16* __restrict__ dwo, float qscale) {
  __shared__ float tile[32][33];
  const int z = blockIdx.z;
  const float* w = (z == 0) ? w0 : (z == 1) ? w1 : (z == 2) ? w2 : w3;
  u16* wt = (z < 3) ? (dqkv + (size_t)z * 1024 * 1024) : dwo;
  const float scale = (z == 0) ? qscale : 1.f;
  const int n0 = blockIdx.x * 32, k0 = blockIdx.y * 32;
  const int tx = threadIdx.x, ty = threadIdx.y;
#pragma unroll
  for (int i = 0; i < 4; ++i)
    tile[ty + i * 8][tx] = w[(size_t)(k0 + ty + i * 8) * 1024 + n0 + tx];
  __syncthreads();
#pragma unroll
  for (int i = 0; i < 4; ++i)
    wt[(size_t)(n0 + ty + i * 8) * 1024 + k0 + tx] = f2bf(tile[tx][ty + i * 8] * scale);
}

// ---------- bias concat (bq pre-scaled) ----------
__global__ __launch_bounds__(256) void pack_bias(
    const float* __restrict__ a, const float* __restrict__ b,
    const float* __restrict__ c, float* __restrict__ o, float qscale) {
  const int i = blockIdx.x * 256 + threadIdx.x;
  o[i] = (i < 1024) ? a[i] * qscale : ((i < 2048) ? b[i - 1024] : c[i - 2048]);
}

// ---------- mask bias (log2 domain) + per-batch all-live flag ----------
__global__ __launch_bounds__(256) void mk_mbias(
    const int* __restrict__ mask, float* __restrict__ mb, int* __restrict__ flags) {
  const int b = blockIdx.x, t = threadIdx.x;
  __shared__ int bad;
  if (t == 0) bad = 0;
  __syncthreads();
  int loc = 0;
#pragma unroll
  for (int i = 0; i < 8; ++i) {
    const int idx = b * 2048 + t * 8 + i;
    const int mv = mask[idx];
    mb[idx] = mv ? 0.f : -1.4427e9f;
    loc |= (mv == 0);
  }
  if (loc) atomicOr(&bad, 1);
  __syncthreads();
  if (t == 0) flags[b] = !bad;
}

// ---------- GEMM: ring-DEPTH, counted vmcnt, 512 threads, BM=128/BN=256 ----------
// EPI 2: bf16 relu out.  EPI 3: QKV split + V-transpose.
// EPI 4: bf16 out = acc+bias+res_f32.   EPI 5: f32 out = acc+bias+res_bf16.
template <int EPI, int DEPTH>
__global__ __launch_bounds__(512, 4) void gemm8(
    const u16* __restrict__ A, const u16* __restrict__ Bt,
    const float* __restrict__ bias, const void* __restrict__ res,
    void* __restrict__ Cout, u16* __restrict__ vt, int M, int N, int K) {
  constexpr int BM = 128, BN = 256;
  constexpr int VMC = 3;
  constexpr int PD = DEPTH - 1;
  constexpr int MF = 4;
  extern __shared__ u16 smem[];             // [DEPTH][BM*32] A + [DEPTH][BN*32] B
  u16* Asb = smem;
  u16* Bsb = smem + DEPTH * BM * 32;

  const int tid = threadIdx.x;
  const int l = tid & 63;
  const int w = tid >> 6;
  const int wr = w >> 2, wc = w & 3;
  const int gx = gridDim.x;
  int id = blockIdx.y * gx + blockIdx.x;
  const int nwg = gx * gridDim.y;
  id = (id & 7) * (nwg >> 3) + (id >> 3);
  const int n0 = (id % gx) * BN;
  const int m0 = (id / gx) * BM;
  const int lr = l & 15, lg = l >> 4;
  const int koff = (lg ^ ((lr >> 1) & 3)) * 8;

  f32x4 acc[MF][4];
#pragma unroll
  for (int i = 0; i < MF; ++i)
#pragma unroll
    for (int j = 0; j < 4; ++j) acc[i][j] = f32x4{0.f, 0.f, 0.f, 0.f};

  const u16* aSrc;
  int aOff;
  {
    const int ci = tid;
    const int row = ci >> 2, c = ci & 3;
    const int sc = c ^ ((row >> 1) & 3);
    aSrc = A + (size_t)(m0 + row) * K + sc * 8;
    aOff = ci * 8;
  }
  const u16* bSrc[2];
  int bOff[2];
#pragma unroll
  for (int i = 0; i < 2; ++i) {
    const int ci = tid + i * 512;
    const int row = ci >> 2, c = ci & 3;
    const int sc = c ^ ((row >> 1) & 3);
    bSrc[i] = Bt + (size_t)(n0 + row) * K + sc * 8;
    bOff[i] = ci * 8;
  }

  const int NT = K >> 5;
  // prologue: stage tiles 0..PD-1
#pragma unroll
  for (int s = 0; s < PD; ++s) {
    gld_lds16(aSrc + s * 32, Asb + s * BM * 32 + aOff);
#pragma unroll
    for (int i = 0; i < 2; ++i) gld_lds16(bSrc[i] + s * 32, Bsb + s * BN * 32 + bOff[i]);
  }
  if constexpr ((PD - 1) * VMC == 3) asm volatile("s_waitcnt vmcnt(3)" ::: "memory");
  else asm volatile("s_waitcnt vmcnt(6)" ::: "memory");
  __builtin_amdgcn_s_barrier();

  int cur = 0;
  for (int t = 0; t < NT; ++t) {
    if (t + PD < NT) {
      int nx = cur + PD;
      if (nx >= DEPTH) nx -= DEPTH;
      const int ko = (t + PD) * 32;
      gld_lds16(aSrc + ko, Asb + nx * BM * 32 + aOff);
#pragma unroll
      for (int i = 0; i < 2; ++i) gld_lds16(bSrc[i] + ko, Bsb + nx * BN * 32 + bOff[i]);
    }
    const u16* Ab = Asb + cur * BM * 32;
    const u16* Bb = Bsb + cur * BN * 32;
    bf16x8 a[MF], b[4];
#pragma unroll
    for (int mf = 0; mf < MF; ++mf)
      a[mf] = *reinterpret_cast<const bf16x8*>(&Ab[(wr * (BM / 2) + mf * 16 + lr) * 32 + koff]);
#pragma unroll
    for (int nf = 0; nf < 4; ++nf)
      b[nf] = *reinterpret_cast<const bf16x8*>(&Bb[(wc * 64 + nf * 16 + lr) * 32 + koff]);
    __builtin_amdgcn_s_setprio(1);
#pragma unroll
    for (int mf = 0; mf < MF; ++mf)
#pragma unroll
      for (int nf = 0; nf < 4; ++nf)
        acc[mf][nf] = __builtin_amdgcn_mfma_f32_16x16x32_bf16(a[mf], b[nf], acc[mf][nf], 0, 0, 0);
    __builtin_amdgcn_s_setprio(0);
    {
      const int ahead = NT - 2 - t;
      if constexpr (PD == 2) {
        if (ahead >= 1) asm volatile("s_waitcnt vmcnt(3)" ::: "memory");
        else asm volatile("s_waitcnt vmcnt(0)" ::: "memory");
      } else {  // PD == 3
        if (ahead >= 2) asm volatile("s_waitcnt vmcnt(6)" ::: "memory");
        else if (ahead == 1) asm volatile("s_waitcnt vmcnt(3)" ::: "memory");
        else asm volatile("s_waitcnt vmcnt(0)" ::: "memory");
      }
    }
    __builtin_amdgcn_s_barrier();
    cur = (cur + 1 >= DEPTH) ? 0 : cur + 1;
  }

  if (EPI == 3 && n0 >= 2048) {
#pragma unroll
    for (int mf = 0; mf < MF; ++mf) {
#pragma unroll
      for (int nf = 0; nf < 4; ++nf) {
        const int col = n0 + wc * 64 + nf * 16 + lr;
        const float bv = bias[col];
        const int row0 = m0 + wr * (BM / 2) + mf * 16 + lg * 4;
        const int bb = row0 >> 11, s0 = row0 & 2047;
        const int d = col - 2048;
        uint2 pv;
        pv.x = cvt_pk_bf16(acc[mf][nf][0] + bv, acc[mf][nf][1] + bv);
        pv.y = cvt_pk_bf16(acc[mf][nf][2] + bv, acc[mf][nf][3] + bv);
        *reinterpret_cast<uint2*>(vt + ((size_t)bb * 1024 + d) * 2048 + s0) = pv;
      }
    }
    return;
  }

#pragma unroll
  for (int mf = 0; mf < MF; ++mf) {
#pragma unroll
    for (int nf = 0; nf < 4; ++nf) {
      const int col = n0 + wc * 64 + nf * 16 + lr;
      const float bv = bias[col];
#pragma unroll
      for (int j = 0; j < 4; ++j) {
        const int row = m0 + wr * (BM / 2) + mf * 16 + lg * 4 + j;
        const size_t idx = (size_t)row * N + col;
        const float vv = acc[mf][nf][j] + bv;
        if (EPI == 4)
          ((u16*)Cout)[idx] = f2bf(vv + ((const float*)res)[idx]);
        else if (EPI == 5)
          ((float*)Cout)[idx] = vv + bf2f(((const u16*)res)[idx]);
        else if (EPI == 2)
          ((u16*)Cout)[idx] = f2bf(fmaxf(vv, 0.f));
        else
          ((u16*)Cout)[idx] = f2bf(vv);
      }
    }
  }
}

// ---------- flash attention: 8 waves, 256 q-rows/block, dbuf K/V, 32KB LDS ----------
// qkv: [B*S][3072] bf16 (Q pre-scaled to exp2 domain at +0, K at +1024).
// vt: [B][1024][2048] bf16. mbias: [B][2048] f32 (log2 domain). flags: [B] all-live.
// grid MUST be dim3(8, 64): head-local XCD swizzle keeps each head's K/V in one XCD's L2.
__global__ __launch_bounds__(512, 4) void attn_fwd9(
    const u16* __restrict__ qkv, const u16* __restrict__ vt,
    const float* __restrict__ mbias, const int* __restrict__ flags,
    u16* __restrict__ ctx) {
  __shared__ u16 Ks[2][64 * 64];
  __shared__ u16 Vs[2][64 * 64];
  const int tid = threadIdx.x;
  const int l = tid & 63;
  const int w = tid >> 6;                   // 0..7
  const int p = blockIdx.y * 8 + blockIdx.x;
  const int idx = p >> 3;                   // 0..63
  const int bh = (p & 7) * 8 + (idx >> 3);  // 0..63
  const int qx = idx & 7;                   // 0..7
  const int b = bh >> 4, h = bh & 15;
  const int r0 = qx * 256 + w * 32;
  const int lr = l & 15, lg = l >> 4;

  const u16* qb = qkv + (size_t)b * 2048 * 3072 + h * 64;
  const u16* kp = qb + 1024;
  const u16* vb = vt + ((size_t)b * 1024 + h * 64) * 2048;
  const float* mb = mbias + (size_t)b * 2048;
  const int allLive = flags[b];

  bf16x8 qf[2][2];
#pragma unroll
  for (int m = 0; m < 2; ++m)
#pragma unroll
    for (int ks = 0; ks < 2; ++ks)
      qf[m][ks] = *reinterpret_cast<const bf16x8*>(
          qb + (size_t)(r0 + m * 16 + lr) * 3072 + ks * 32 + lg * 8);

  bf16x8 ones;
#pragma unroll
  for (int e = 0; e < 8; ++e) ones[e] = (__bf16)1.0f;

  float mrun[2] = {-1e30f, -1e30f};
  f32x4 osum[2];
  f32x4 o[2][4];
#pragma unroll
  for (int m = 0; m < 2; ++m) {
    osum[m] = f32x4{0.f, 0.f, 0.f, 0.f};
#pragma unroll
    for (int d = 0; d < 4; ++d) o[m][d] = f32x4{0.f, 0.f, 0.f, 0.f};
  }

  const int srow = tid >> 3, scc = tid & 7;
  const int ssc = scc ^ (srow & 7);
  const u16* kS = kp + (size_t)srow * 3072 + ssc * 8;
  const u16* vS = vb + (size_t)srow * 2048 + ssc * 8;
  gld_lds16(kS, &Ks[0][tid * 8]);
  gld_lds16(vS, &Vs[0][tid * 8]);
  asm volatile("s_waitcnt vmcnt(0)" ::: "memory");
  __syncthreads();

  union U8 { unsigned u[4]; bf16x8 v; };

  int cur = 0;
  for (int t = 0; t < 32; ++t) {
    const int kb0 = t * 64;
    if (t + 1 < 32) {
      const int nb = kb0 + 64;
      gld_lds16(kS + (size_t)nb * 3072, &Ks[cur ^ 1][tid * 8]);
      gld_lds16(vS + nb, &Vs[cur ^ 1][tid * 8]);
    }

    f32x4 st[2][4];
    __builtin_amdgcn_s_setprio(1);
#pragma unroll
    for (int cf = 0; cf < 4; ++cf) {
      const int krow = cf * 16 + lr;
      const int ch0 = lg ^ (krow & 7);
      const int ch1 = (4 + lg) ^ (krow & 7);
      const bf16x8 kf0 = *reinterpret_cast<const bf16x8*>(&Ks[cur][krow * 64 + ch0 * 8]);
      const bf16x8 kf1 = *reinterpret_cast<const bf16x8*>(&Ks[cur][krow * 64 + ch1 * 8]);
#pragma unroll
      for (int m = 0; m < 2; ++m) {
        f32x4 acc = __builtin_amdgcn_mfma_f32_16x16x32_bf16(kf0, qf[m][0],
                                                            f32x4{0.f, 0.f, 0.f, 0.f}, 0, 0, 0);
        st[m][cf] = __builtin_amdgcn_mfma_f32_16x16x32_bf16(kf1, qf[m][1], acc, 0, 0, 0);
      }
    }
    __builtin_amdgcn_s_setprio(0);

    if (!allLive) {
#pragma unroll
      for (int cf = 0; cf < 4; ++cf) {
        const float4 m4 = *reinterpret_cast<const float4*>(mb + kb0 + cf * 16 + lg * 4);
#pragma unroll
        for (int m = 0; m < 2; ++m) {
          st[m][cf][0] += m4.x;
          st[m][cf][1] += m4.y;
          st[m][cf][2] += m4.z;
          st[m][cf][3] += m4.w;
        }
      }
    }

    bf16x8 paA[2], paB[2];
#pragma unroll
    for (int m = 0; m < 2; ++m) {
      float p0 = fmaxf(fmaxf(st[m][0][0], st[m][0][1]), st[m][0][2]);
      float p1 = fmaxf(fmaxf(st[m][0][3], st[m][1][0]), st[m][1][1]);
      float p2 = fmaxf(fmaxf(st[m][1][2], st[m][1][3]), st[m][2][0]);
      float p3 = fmaxf(fmaxf(st[m][2][1], st[m][2][2]), st[m][2][3]);
      float p4 = fmaxf(fmaxf(st[m][3][0], st[m][3][1]), st[m][3][2]);
      float pm = fmaxf(fmaxf(p0, p1), p2);
      pm = fmaxf(fmaxf(pm, p3), p4);
      pm = fmaxf(pm, st[m][3][3]);
      pm = fmaxf(pm, __shfl_xor(pm, 16));
      pm = fmaxf(pm, __shfl_xor(pm, 32));
      if (__any(pm > mrun[m] + 8.f)) {          // defer-max (T13)
        const float mn = fmaxf(mrun[m], pm);
        const float corr = exp2f(mrun[m] - mn);
        mrun[m] = mn;
#pragma unroll
        for (int j = 0; j < 4; ++j) osum[m][j] *= corr;
#pragma unroll
        for (int d = 0; d < 4; ++d)
#pragma unroll
          for (int j = 0; j < 4; ++j) o[m][d][j] *= corr;
      }
#pragma unroll
      for (int cf = 0; cf < 4; ++cf)
#pragma unroll
        for (int j = 0; j < 4; ++j)
          st[m][cf][j] = exp2f(st[m][cf][j] - mrun[m]);

      unsigned pk[4][2];
#pragma unroll
      for (int cf = 0; cf < 4; ++cf)
#pragma unroll
        for (int wp = 0; wp < 2; ++wp)
          pk[cf][wp] = cvt_pk_bf16(st[m][cf][2 * wp], st[m][cf][2 * wp + 1]);

      U8 a0, a1;
#pragma unroll
      for (int c = 0; c < 2; ++c) {
        const int src = lr + 16 * ((2 * lg + c) & 3);
#pragma unroll
        for (int wp = 0; wp < 2; ++wp) {
          const int v00 = __shfl((int)pk[0][wp], src);
          const int v01 = __shfl((int)pk[1][wp], src);
          const int v10 = __shfl((int)pk[2][wp], src);
          const int v11 = __shfl((int)pk[3][wp], src);
          a0.u[2 * c + wp] = (unsigned)((lg < 2) ? v00 : v01);
          a1.u[2 * c + wp] = (unsigned)((lg < 2) ? v10 : v11);
        }
      }
      paA[m] = a0.v;
      paB[m] = a1.v;
    }

    __builtin_amdgcn_s_setprio(1);
#pragma unroll
    for (int df = 0; df < 4; ++df) {
      const int vrow = df * 16 + lr;
      const int ch0 = lg ^ (vrow & 7);
      const int ch1 = (4 + lg) ^ (vrow & 7);
      const bf16x8 vf0 = *reinterpret_cast<const bf16x8*>(&Vs[cur][vrow * 64 + ch0 * 8]);
      const bf16x8 vf1 = *reinterpret_cast<const bf16x8*>(&Vs[cur][vrow * 64 + ch1 * 8]);
#pragma unroll
      for (int m = 0; m < 2; ++m) {
        o[m][df] = __builtin_amdgcn_mfma_f32_16x16x32_bf16(vf0, paA[m], o[m][df], 0, 0, 0);
        o[m][df] = __builtin_amdgcn_mfma_f32_16x16x32_bf16(vf1, paB[m], o[m][df], 0, 0, 0);
      }
    }
#pragma unroll
    for (int m = 0; m < 2; ++m) {
      osum[m] = __builtin_amdgcn_mfma_f32_16x16x32_bf16(ones, paA[m], osum[m], 0, 0, 0);
      osum[m] = __builtin_amdgcn_mfma_f32_16x16x32_bf16(ones, paB[m], osum[m], 0, 0, 0);
    }
    __builtin_amdgcn_s_setprio(0);

    asm volatile("s_waitcnt vmcnt(0)" ::: "memory");
    __syncthreads();
    cur ^= 1;
  }

#pragma unroll
  for (int m = 0; m < 2; ++m) {
    const float rdiv = 1.f / osum[m][0];
    const size_t rowbase = ((size_t)b * 2048 + r0 + m * 16 + lr) * 1024 + h * 64;
#pragma unroll
    for (int df = 0; df < 4; ++df) {
      uint2 s4;
      s4.x = cvt_pk_bf16(o[m][df][0] * rdiv, o[m][df][1] * rdiv);
      s4.y = cvt_pk_bf16(o[m][df][2] * rdiv, o[m][df][3] * rdiv);
      *reinterpret_cast<uint2*>(ctx + rowbase + df * 16 + lg * 4) = s4;
    }
  }
}

// ---------- launch ----------
extern "C" void kernel_launch(void* const* d_in, const int* in_sizes, int n_in,
                              void* d_out, int out_size, void* d_ws, size_t ws_size,
                              hipStream_t stream) {
  const float* x = (const float*)d_in[0];
  const int* mask = (const int*)d_in[1];
  const float* wq = (const float*)d_in[2];
  const float* bq = (const float*)d_in[3];
  const float* wk = (const float*)d_in[4];
  const float* bk = (const float*)d_in[5];
  const float* wv = (const float*)d_in[6];
  const float* bv = (const float*)d_in[7];
  const float* wo = (const float*)d_in[8];
  const float* bo = (const float*)d_in[9];
  const float* w1 = (const float*)d_in[10];
  const float* b1 = (const float*)d_in[11];
  const float* w2 = (const float*)d_in[12];
  const float* b2 = (const float*)d_in[13];
  const float* ln1a = (const float*)d_in[14];
  const float* ln1b = (const float*)d_in[15];
  const float* ln2a = (const float*)d_in[16];
  const float* ln2b = (const float*)d_in[17];

  const float SCL2 = 0.125f * 1.4426950408889634f;  // 1/sqrt(dk) * log2(e)
  const size_t LDS128_3 = 3 * (128 + 256) * 32 * sizeof(u16);  // 73728
  const size_t LDS128_4 = 4 * (128 + 256) * 32 * sizeof(u16);  // 98304

  (void)hipFuncSetAttribute((const void*)&gemm8<3, 3>,
                            hipFuncAttributeMaxDynamicSharedMemorySize, (int)LDS128_3);
  (void)hipFuncSetAttribute((const void*)&gemm8<2, 3>,
                            hipFuncAttributeMaxDynamicSharedMemorySize, (int)LDS128_3);
  (void)hipFuncSetAttribute((const void*)&gemm8<4, 4>,
                            hipFuncAttributeMaxDynamicSharedMemorySize, (int)LDS128_4);
  (void)hipFuncSetAttribute((const void*)&gemm8<5, 4>,
                            hipFuncAttributeMaxDynamicSharedMemorySize, (int)LDS128_4);

  char* ws = (char*)d_ws;
  const size_t MB = 1024ull * 1024ull;
  u16* WTQKV = (u16*)(ws + 0 * MB);    // [3072][1024] bf16, 6MB
  u16* WTO = (u16*)(ws + 6 * MB);      // 2MB
  u16* W1T = (u16*)(ws + 8 * MB);      // [4096][1024], 8MB
  u16* W2T = (u16*)(ws + 16 * MB);     // [1024][4096], 8MB
  float* BQKV = (float*)(ws + 24 * MB);              // 12KB
  float* MBIAS = (float*)(ws + 24 * MB + 65536);     // 32KB
  int* FLAGS = (int*)(ws + 24 * MB + 131072);        // 16B
  u16* QKV = (u16*)(ws + 25 * MB);     // [8192][3072] bf16 (Q,K cols used), 48MB (25-73)
  u16* VT = (u16*)(ws + 73 * MB);      // [4][1024][2048] bf16, 16MB (73-89)
  u16* XN = (u16*)(ws + 89 * MB);      // 16MB (89-105); dead after QKV gemm
  u16* CTX = (u16*)(ws + 105 * MB);    // 16MB (105-121)
  u16* X2 = (u16*)(ws + 25 * MB);      // bf16 residual stream, 16MB (25-41), overwrites QKV
  u16* XN2 = (u16*)(ws + 57 * MB);     // 16MB (57-73)
  u16* H1 = (u16*)(ws + 73 * MB);      // [8192][4096] bf16, 64MB (73-137)

  dim3 bt(32, 8);
  // fused 4x 1024^2 weight converts (wq scaled), then the two FFN weights
  wcvt_t4<<<dim3(32, 32, 4), bt, 0, stream>>>(wq, wk, wv, wo, WTQKV, WTO, SCL2);
  wcvt_t<<<dim3(128, 32), bt, 0, stream>>>(w1, W1T, 1024, 4096, 1.f);
  wcvt_t<<<dim3(32, 128), bt, 0, stream>>>(w2, W2T, 4096, 1024, 1.f);
  pack_bias<<<dim3(12), 256, 0, stream>>>(bq, bk, bv, BQKV, SCL2);
  mk_mbias<<<dim3(4), 256, 0, stream>>>(mask, MBIAS, FLAGS);

  ln_kernel<<<8192, 256, 0, stream>>>(x, XN, ln1a, ln1b);
  // fused QKV projection (128x256 tiles, ring-3); V written transposed to VT
  gemm8<3, 3><<<dim3(12, 64), 512, LDS128_3, stream>>>(XN, WTQKV, BQKV, nullptr, QKV, VT, 8192, 3072, 1024);
  attn_fwd9<<<dim3(8, 64), 512, 0, stream>>>(QKV, VT, MBIAS, FLAGS, CTX);
  // O-proj + residual -> bf16 X2 (1 block/CU -> ring-4 depth-3 prefetch)
  gemm8<4, 4><<<dim3(4, 64), 512, LDS128_4, stream>>>(CTX, WTO, bo, x, X2, nullptr, 8192, 1024, 1024);
  ln_kernel_bf<<<8192, 256, 0, stream>>>(X2, XN2, ln2a, ln2b);
  // FFN1 (128x256 tiles, ring-3, 2 blocks/CU)
  gemm8<2, 3><<<dim3(16, 64), 512, LDS128_3, stream>>>(XN2, W1T, b1, nullptr, H1, nullptr, 8192, 4096, 1024);
  // FFN2 + bf16 residual -> f32 d_out (1 block/CU -> ring-4)
  gemm8<5, 4><<<dim3(4, 64), 512, LDS128_4, stream>>>(H1, W2T, b2, X2, (float*)d_out, nullptr, 8192, 1024, 4096);
}